// Round 8
// baseline (117.035 us; speedup 1.0000x reference)
//
#include <hip/hip_runtime.h>
#include <float.h>
#include <math.h>

#define NODE_DIM 256
#define HIDDEN   128
#define HEADS    8
#define HEAD_DIM 16
#define NB       768
#define BATCH    2
#define NNODES   (BATCH * NB)
#define SEPP     200   // f16 row stride: 400 B = 100 dwords, 100%32=4 (2-way, free)
#define REC      144   // partial record: 128 num + 8 m + 8 sum
#define NSPL     4     // K-splits per (b, query-pair)
#define NTH      128   // theta bins (power of 2, wraps)
#define NR       128   // radius bins
#define RMAX     16.0f
#define NTB      (NTH * NR / 256)   // table-build blocks (64)

typedef _Float16 f16;
typedef _Float16 h2 __attribute__((ext_vector_type(2)));
typedef __fp16 fp16x2 __attribute__((ext_vector_type(2)));
union F2H { float f; h2 h; unsigned u; };
union V4H { float4 f; h2 h[4]; };

__device__ __forceinline__ h2 pkrtz(float a, float b) {
  fp16x2 r = __builtin_amdgcn_cvt_pkrtz(a, b);   // v_cvt_pkrtz_f16_f32
  return __builtin_bit_cast(h2, r);
}

// GELU = u*Phi(u), Phi(u) ~ 0.5 + u*R(u^2), cubic fit on [-2.5,2.5].
__device__ __forceinline__ float gelu_poly(float u) {
  u = fminf(fmaxf(u, -2.5f), 2.5f);
  float t = u * u;
  float r = fmaf(t, -4.08639e-4f, 7.64400e-3f);
  r = fmaf(t, r, -6.40405e-2f);
  r = fmaf(t, r, 3.985355e-1f);
  return u * fmaf(u, r, 0.5f);
}

// Bilinear (theta, r)-table lookup of the 8-head edge bias; adds into the
// 8 score rows at column k0 (rows SEPP apart).
__device__ __forceinline__ void bias_lookup(
    const float* __restrict__ tab, const float* __restrict__ tab0,
    float dx, float dy, f16* __restrict__ row) {
  float sq = fmaf(dx, dx, dy * dy);
  float dist = __builtin_amdgcn_sqrtf(sq + 1e-6f);
  // fast atan2 (err ~1e-6 rad)
  float ax = fabsf(dx), ay = fabsf(dy);
  float mx = fmaxf(ax, ay), mn = fminf(ax, ay);
  float q = mn * __builtin_amdgcn_rcpf(mx);
  float s2 = q * q;
  float at = fmaf(s2, -0.01172120f, 0.05265332f);
  at = fmaf(s2, at, -0.11643287f);
  at = fmaf(s2, at, 0.19354346f);
  at = fmaf(s2, at, -0.33262347f);
  at = fmaf(s2, at, 0.99997726f);
  at = at * q;
  at = (ay > ax) ? (1.570796327f - at) : at;
  at = (dx < 0.f) ? (3.141592653f - at) : at;
  at = (dy < 0.f) ? -at : at;                    // theta in (-pi, pi]
  float tf = at * (0.1591549431f * (float)NTH);  // turns * NTH
  float tff = floorf(tf);
  float ft = tf - tff;
  int ti0 = (int)tff & (NTH - 1), ti1 = (ti0 + 1) & (NTH - 1);
  float rf = fminf(dist * ((float)(NR - 1) / RMAX), (float)(NR - 1) - 1e-3f);
  float rff = floorf(rf);
  float fr = rf - rff;
  int ri0 = (int)rff, ri1 = ri0 + 1;
  const float4* T4 = (const float4*)tab;
  V4H c00, c01, c10, c11;
  c00.f = T4[ri0 * NTH + ti0];
  c01.f = T4[ri0 * NTH + ti1];
  c10.f = T4[ri1 * NTH + ti0];
  c11.f = T4[ri1 * NTH + ti1];
  if (sq < 1e-12f) {      // degenerate (diagonal): exact tab0, kill NaN weights
    c00.f = *(const float4*)tab0;
    ft = 0.f; fr = 0.f;
  }
  float w11 = ft * fr, w10 = fr - w11, w01 = ft - w11;
  float w00 = 1.f - ft - fr + w11;
  h2 W00 = pkrtz(w00, w00), W01 = pkrtz(w01, w01);
  h2 W10 = pkrtz(w10, w10), W11 = pkrtz(w11, w11);
#pragma unroll
  for (int p = 0; p < 4; ++p) {
    h2 bb = c00.h[p] * W00 + c01.h[p] * W01;
    bb = c10.h[p] * W10 + bb;
    bb = c11.h[p] * W11 + bb;
    f16* r0p = row + (2 * p) * SEPP;
    f16* r1p = row + (2 * p + 1) * SEPP;
    *r0p = (f16)(*r0p + bb.x);
    *r1p = (f16)(*r1p + bb.y);
  }
}

// == K1: QKV (0..383) + compaction (384,385) + b2m (386) + WoP (387)
//       + edge-bias table build (388..388+NTB-1) ==============================
__global__ __launch_bounds__(256) void prep_kernel(
    const float* __restrict__ nf, const float* __restrict__ pos,
    const int* __restrict__ mask,
    const float* __restrict__ Wq, const float* __restrict__ Wk,
    const float* __restrict__ Wv, const float* __restrict__ W1,
    const float* __restrict__ b1, const float* __restrict__ W2,
    const float* __restrict__ b2, const float* __restrict__ Wo,
    float* __restrict__ qc, f16* __restrict__ kTcH, f16* __restrict__ vcH,
    unsigned* __restrict__ WoP,
    float* __restrict__ tab, float* __restrict__ tab0,
    float* __restrict__ b2m,
    float* __restrict__ pcx, float* __restrict__ pcy,
    int* __restrict__ vlist, int* __restrict__ mlist, int* __restrict__ cnt) {
  int blk = blockIdx.x, t = threadIdx.x;

  if (blk < NNODES / 4) {
    int n0 = blk * 4;
    int b = n0 / NB;
    int lo = n0 - b * NB;
    __shared__ int accv;
    if (t == 0) accv = 0;
    __syncthreads();
    for (int jb = 0; jb < lo; jb += 256) {
      int j = jb + t;
      int mv = (j < lo) && (mask[b * NB + j] != 0);
      unsigned long long ball = __ballot(mv);
      if ((t & 63) == 0) atomicAdd(&accv, __popcll(ball));
    }
    __syncthreads();
    int cb = accv;
    int m0 = mask[n0] != 0, m1 = mask[n0 + 1] != 0, m2 = mask[n0 + 2] != 0,
        m3 = mask[n0 + 3] != 0;
    int civ[4] = {cb, cb + m0, cb + m0 + m1, cb + m0 + m1 + m2};
    int mv4[4] = {m0, m1, m2, m3};

    const float* x0 = nf + (size_t)(n0 + 0) * NODE_DIM;
    const float* x1 = nf + (size_t)(n0 + 1) * NODE_DIM;
    const float* x2 = nf + (size_t)(n0 + 2) * NODE_DIM;
    const float* x3 = nf + (size_t)(n0 + 3) * NODE_DIM;
    for (int id = t; id < 3 * HIDDEN; id += 256) {
      int m = id >> 7, c = id & 127;
      const float* W = (m == 0) ? Wq : (m == 1) ? Wk : Wv;
      float a0 = 0.f, a1 = 0.f, a2 = 0.f, a3 = 0.f;
      float e0 = 0.f, e1 = 0.f, e2 = 0.f, e3 = 0.f;
#pragma unroll 8
      for (int kk = 0; kk < NODE_DIM; kk += 2) {
        float w0 = W[kk * HIDDEN + c];
        float w1 = W[(kk + 1) * HIDDEN + c];
        a0 = fmaf(x0[kk], w0, a0);  e0 = fmaf(x0[kk + 1], w1, e0);
        a1 = fmaf(x1[kk], w0, a1);  e1 = fmaf(x1[kk + 1], w1, e1);
        a2 = fmaf(x2[kk], w0, a2);  e2 = fmaf(x2[kk + 1], w1, e2);
        a3 = fmaf(x3[kk], w0, a3);  e3 = fmaf(x3[kk + 1], w1, e3);
      }
      float acc[4] = {a0 + e0, a1 + e1, a2 + e2, a3 + e3};
#pragma unroll
      for (int n = 0; n < 4; ++n) {
        if (mv4[n]) {
          int slot = b * NB + civ[n];
          if (m == 0)      qc[(size_t)slot * HIDDEN + c] = acc[n];
          else if (m == 1) kTcH[((size_t)b * HIDDEN + c) * NB + civ[n]] = (f16)acc[n];
          else             vcH[(size_t)slot * HIDDEN + c] = (f16)acc[n];
        }
      }
    }
  } else if (blk < NNODES / 4 + 2) {
    int b = blk - NNODES / 4;
    __shared__ int wcnt[4];
    __shared__ int base2[2];
    if (t < 2) base2[t] = 0;
    __syncthreads();
    int lane = t & 63, w = t >> 6;
    for (int iter = 0; iter < NB / 256; ++iter) {
      int j = iter * 256 + t;
      int mv = mask[b * NB + j] != 0;
      unsigned long long ball = __ballot(mv);
      if (lane == 0) wcnt[w] = __popcll(ball);
      __syncthreads();
      int pv = 0;
      for (int i = 0; i < w; ++i) pv += wcnt[i];
      int pin = (lane == 0) ? 0 : __popcll(ball & (~0ull >> (64 - lane)));
      if (mv) {
        int p = base2[0] + pv + pin;
        vlist[b * NB + p] = j;
        pcx[b * NB + p] = pos[(b * NB + j) * 2];
        pcy[b * NB + p] = pos[(b * NB + j) * 2 + 1];
      } else {
        int pm = base2[1] + (w * 64 - pv) + (lane - pin);
        mlist[b * NB + pm] = j;
      }
      __syncthreads();
      if (t == 0) {
        int tot = wcnt[0] + wcnt[1] + wcnt[2] + wcnt[3];
        base2[0] += tot;
        base2[1] += 256 - tot;
      }
      __syncthreads();
    }
    int nv = base2[0];
    if (t == 0) cnt[b] = nv;
    int nvp8 = (nv + 7) & ~7;
    if (t < HIDDEN)
      for (int col = nv; col < nvp8; ++col)
        kTcH[((size_t)b * HIDDEN + t) * NB + col] = (f16)0.0f;
  } else if (blk == NNODES / 4 + 2) {
    if (t < HEADS) {
      float s = 0.0f;
      for (int d = 0; d < HEAD_DIM; ++d) s += b2[t * HEAD_DIM + d];
      b2m[t] = s * (1.0f / 16.0f);
    }
  } else if (blk == NNODES / 4 + 3) {
    for (int k2 = 0; k2 < 64; ++k2) {
      F2H w;
      w.h = (h2){(f16)Wo[(2 * k2) * NODE_DIM + t],
                 (f16)Wo[(2 * k2 + 1) * NODE_DIM + t]};
      WoP[k2 * 256 + t] = w.u;
    }
  } else {
    // ---- edge-bias table: tab[ri][ti] = 8 x f16 of F(theta_ti, r_ri) ----
    int tblk = blk - (NNODES / 4 + 4);
    __shared__ float4 w1p[HIDDEN];           // {W1x, W1y, W1d, b1}
    __shared__ float  w2f[HIDDEN * 8];       // head-summed W2 / 16
    if (t < HIDDEN)
      w1p[t] = make_float4(W1[t], W1[HIDDEN + t], W1[2 * HIDDEN + t], b1[t]);
    for (int idx = t; idx < HIDDEN * 8; idx += 256) {
      int c = idx >> 3, h = idx & 7;
      float s = 0.f;
#pragma unroll
      for (int d = 0; d < HEAD_DIM; ++d) s += W2[c * HIDDEN + h * HEAD_DIM + d];
      w2f[idx] = s * (1.0f / 16.0f);
    }
    __syncthreads();
    int pid = tblk * 256 + t;
    int ti = pid & (NTH - 1), ri = pid >> 7;          // pid / NTH
    float th = (float)ti * (6.283185307f / (float)NTH);
    float r = (float)ri * (RMAX / (float)(NR - 1));
    float ux = __cosf(th), uy = __sinf(th);
    float acc[8] = {0, 0, 0, 0, 0, 0, 0, 0};
    for (int c = 0; c < HIDDEN; ++c) {
      float4 w = w1p[c];
      float u = fmaf(ux, w.x, fmaf(uy, w.y, fmaf(r, w.z, w.w)));
      float g = gelu_poly(u);
      const float4* wp = (const float4*)(w2f + c * 8);
      float4 wa = wp[0], wb = wp[1];
      acc[0] = fmaf(g, wa.x, acc[0]); acc[1] = fmaf(g, wa.y, acc[1]);
      acc[2] = fmaf(g, wa.z, acc[2]); acc[3] = fmaf(g, wa.w, acc[3]);
      acc[4] = fmaf(g, wb.x, acc[4]); acc[5] = fmaf(g, wb.y, acc[5]);
      acc[6] = fmaf(g, wb.z, acc[6]); acc[7] = fmaf(g, wb.w, acc[7]);
    }
    F2H p0, p1, p2, p3;
    p0.h = pkrtz(acc[0], acc[1]); p1.h = pkrtz(acc[2], acc[3]);
    p2.h = pkrtz(acc[4], acc[5]); p3.h = pkrtz(acc[6], acc[7]);
    ((float4*)tab)[ri * NTH + ti] = make_float4(p0.f, p1.f, p2.f, p3.f);
    if (tblk == 0 && t == 0) {
      // degenerate pair value: direction (0,0), dist = 1e-3
      float a0[8] = {0, 0, 0, 0, 0, 0, 0, 0};
      for (int c = 0; c < HIDDEN; ++c) {
        float4 w = w1p[c];
        float g = gelu_poly(fmaf(1e-3f, w.z, w.w));
        const float4* wp = (const float4*)(w2f + c * 8);
        float4 wa = wp[0], wb = wp[1];
        a0[0] = fmaf(g, wa.x, a0[0]); a0[1] = fmaf(g, wa.y, a0[1]);
        a0[2] = fmaf(g, wa.z, a0[2]); a0[3] = fmaf(g, wa.w, a0[3]);
        a0[4] = fmaf(g, wb.x, a0[4]); a0[5] = fmaf(g, wb.y, a0[5]);
        a0[6] = fmaf(g, wb.z, a0[6]); a0[7] = fmaf(g, wb.w, a0[7]);
      }
      F2H q0, q1, q2, q3;
      q0.h = pkrtz(a0[0], a0[1]); q1.h = pkrtz(a0[2], a0[3]);
      q2.h = pkrtz(a0[4], a0[5]); q3.h = pkrtz(a0[6], a0[7]);
      *(float4*)tab0 = make_float4(q0.f, q1.f, q2.f, q3.f);
    }
  }
}

// ===== K2a: split-K partial attention, QBLK=2 queries x NSPL=4 splits. ======
// Block = (split, b, query-pair). Each K/V float4 loaded ONCE for 2 queries;
// 4-way K-split restores 1536 working blocks (6/CU) for latency hiding.
__global__ __launch_bounds__(256) void attn_part_kernel(
    const float* __restrict__ pcx, const float* __restrict__ pcy,
    const int* __restrict__ cnt, const float* __restrict__ tab,
    const float* __restrict__ tab0,
    const float* __restrict__ b2m, const float* __restrict__ qc,
    const f16* __restrict__ kTcH, const f16* __restrict__ vcH,
    float* __restrict__ part) {
  int spl = blockIdx.x & (NSPL - 1), idx = blockIdx.x >> 2;
  int b = idx & 1, cp = idx >> 1;
  int ci0 = 2 * cp, ci1 = ci0 + 1;
  int t = threadIdx.x;
  int nv = cnt[b];
  if (ci0 >= nv) return;                   // both queries masked
  int q1v = (ci1 < nv);
  int slot0 = b * NB + ci0, slot1 = b * NB + ci1;
  int H8 = (((nv + NSPL - 1) / NSPL) + 7) & ~7;   // 8-aligned split size
  int klo = spl * H8;
  int khi = min(nv, klo + H8);
  int kn = khi - klo;                      // <= 200 (nv <= 768)
  float* rec0 = part + ((size_t)slot0 * NSPL + spl) * REC;
  float* rec1 = part + ((size_t)slot1 * NSPL + spl) * REC;

  __shared__ __align__(16) unsigned char smem[15744];
  f16*   sE    = (f16*)smem;                   // [2][8][SEPP] 6400 B
  float* qs    = (float*)(smem + 6400);        // [2][128]     1024 B
  float* partD = (float*)(smem + 7424);        // [16][128]    8192 B
  float* ms    = (float*)(smem + 15616);       // [2][8]       64 B
  float* ss    = (float*)(smem + 15680);       // [2][8]       64 B
  f16* sE0 = sE;
  f16* sE1 = sE + 8 * SEPP;

  if (kn <= 0) {                           // empty split (small nv)
    if (t < 128) { rec0[t] = 0.f; if (q1v) rec1[t] = 0.f; }
    else if (t < 136) { rec0[t] = -3.0e38f; if (q1v) rec1[t] = -3.0e38f; }
    else if (t < 144) { rec0[t] = 0.f; if (q1v) rec1[t] = 0.f; }
    return;
  }

  if (t < HIDDEN) qs[t] = qc[(size_t)slot0 * HIDDEN + t];
  else qs[128 + (t - 128)] = qc[(size_t)slot1 * HIDDEN + (t - 128)];
  float pix0 = pcx[slot0], piy0 = pcy[slot0];
  float pix1 = pcx[slot1], piy1 = pcy[slot1];
  __syncthreads();

  // ---- A: qk dots, K float4 loaded once for both queries ----
  {
    int h = t >> 5, l = t & 31;
    const f16* kb = kTcH + ((size_t)b * HIDDEN + h * 16) * NB + klo;
    h2 qp0[16], qp1[16];
#pragma unroll
    for (int r = 0; r < 16; ++r) {
      f16 qa = (f16)qs[h * 16 + r];
      f16 qb = (f16)qs[128 + h * 16 + r];
      qp0[r] = (h2){qa, qa};
      qp1[r] = (h2){qb, qb};
    }
    h2 sc4 = {(f16)0.25f, (f16)0.25f};
    f16 bhh = (f16)b2m[h];
    h2 bh2 = {bhh, bhh};
    int n8 = (kn + 7) >> 3;
    for (int j8 = l; j8 < n8; j8 += 32) {
      h2 a0[4] = {{0, 0}, {0, 0}, {0, 0}, {0, 0}};
      h2 a1[4] = {{0, 0}, {0, 0}, {0, 0}, {0, 0}};
#pragma unroll
      for (int r = 0; r < 16; ++r) {
        V4H kv;
        kv.f = *(const float4*)(kb + (size_t)r * NB + j8 * 8);
#pragma unroll
        for (int p = 0; p < 4; ++p) {
          a0[p] += qp0[r] * kv.h[p];
          a1[p] += qp1[r] * kv.h[p];
        }
      }
      V4H r0, r1;
#pragma unroll
      for (int p = 0; p < 4; ++p) {
        r0.h[p] = a0[p] * sc4 + bh2;
        r1.h[p] = a1[p] * sc4 + bh2;
      }
      *(float4*)(sE0 + h * SEPP + j8 * 8) = r0.f;
      *(float4*)(sE1 + h * SEPP + j8 * 8) = r1.f;
    }
  }
  __syncthreads();

  // ---- B: edge-MLP bias via table, both queries per key ----
  for (int k0 = t; k0 < kn; k0 += 256) {
    int s0 = b * NB + klo + k0;
    float px = pcx[s0], py = pcy[s0];
    bias_lookup(tab, tab0, pix0 - px, piy0 - py, sE0 + k0);
    if (q1v) bias_lookup(tab, tab0, pix1 - px, piy1 - py, sE1 + k0);
  }
  __syncthreads();

  // ---- C: local softmax stats, 16 (query,head) groups x 16 lanes ----
  {
    int g = t >> 4, l = t & 15;
    int q = g & 1, h = g >> 1;
    f16* row = sE + q * 8 * SEPP + h * SEPP;
    float m = -FLT_MAX;
    for (int jj = l; jj < kn; jj += 16) m = fmaxf(m, (float)row[jj]);
    for (int off = 8; off; off >>= 1) m = fmaxf(m, __shfl_down(m, off, 16));
    m = __shfl(m, 0, 16);
    float s = 0.0f;
    for (int jj = l; jj < kn; jj += 16) {
      float e = __expf((float)row[jj] - m);
      row[jj] = (f16)e;
      s += e;
    }
    for (int off = 8; off; off >>= 1) s += __shfl_down(s, off, 16);
    if (l == 0) { ms[q * 8 + h] = m; ss[q * 8 + h] = s; }
  }
  __syncthreads();

  // ---- D: unnormalized weighted V, V float4 loaded once for both queries ----
  h2 acc0[4] = {{0, 0}, {0, 0}, {0, 0}, {0, 0}};
  h2 acc1[4] = {{0, 0}, {0, 0}, {0, 0}, {0, 0}};
  {
    int o8 = t & 15, g = t >> 4;
    int h = o8 >> 1;
    for (int jj = g; jj < kn; jj += 16) {
      V4H vv;
      vv.f = *(const float4*)(vcH + (size_t)(b * NB + klo + jj) * HIDDEN + o8 * 8);
      f16 w0 = sE0[h * SEPP + jj];
      f16 w1 = sE1[h * SEPP + jj];
      h2 ww0 = {w0, w0}, ww1 = {w1, w1};
#pragma unroll
      for (int p = 0; p < 4; ++p) {
        acc0[p] += ww0 * vv.h[p];
        acc1[p] += ww1 * vv.h[p];
      }
    }
  }
  {
    int o8 = t & 15, g = t >> 4;
    float* pd = partD + g * HIDDEN + o8 * 8;
    pd[0] = (float)acc0[0].x; pd[1] = (float)acc0[0].y;
    pd[2] = (float)acc0[1].x; pd[3] = (float)acc0[1].y;
    pd[4] = (float)acc0[2].x; pd[5] = (float)acc0[2].y;
    pd[6] = (float)acc0[3].x; pd[7] = (float)acc0[3].y;
  }
  __syncthreads();
  if (t < 128) {
    float s = 0.0f;
#pragma unroll
    for (int g = 0; g < 16; ++g) s += partD[g * HIDDEN + t];
    rec0[t] = s;
  } else if (t < 136) {
    rec0[t] = ms[t - 128];
  } else if (t < 144) {
    rec0[t] = ss[t - 136];
  }
  __syncthreads();
  {
    int o8 = t & 15, g = t >> 4;
    float* pd = partD + g * HIDDEN + o8 * 8;
    pd[0] = (float)acc1[0].x; pd[1] = (float)acc1[0].y;
    pd[2] = (float)acc1[1].x; pd[3] = (float)acc1[1].y;
    pd[4] = (float)acc1[2].x; pd[5] = (float)acc1[2].y;
    pd[6] = (float)acc1[3].x; pd[7] = (float)acc1[3].y;
  }
  __syncthreads();
  if (q1v) {
    if (t < 128) {
      float s = 0.0f;
#pragma unroll
      for (int g = 0; g < 16; ++g) s += partD[g * HIDDEN + t];
      rec1[t] = s;
    } else if (t < 136) {
      rec1[t] = ms[8 + t - 128];
    } else if (t < 144) {
      rec1[t] = ss[8 + t - 136];
    }
  }
}

// ===== K2b: flash merge of NSPL partials + out-proj + residual + LN =========
__global__ __launch_bounds__(256) void attn_merge_kernel(
    const int* __restrict__ cnt, const int* __restrict__ vlist,
    const int* __restrict__ mlist, const float* __restrict__ part,
    const unsigned* __restrict__ WoP, const float* __restrict__ nf,
    const float* __restrict__ bo, const float* __restrict__ gamma,
    const float* __restrict__ beta, float* __restrict__ out) {
  int b = blockIdx.x & 1, ci = blockIdx.x >> 1;
  int t = threadIdx.x;
  int nv = cnt[b];
  if (ci >= nv) {                      // masked node -> x==0 -> LN gives beta
    int node = b * NB + mlist[b * NB + (ci - nv)];
    out[(size_t)node * NODE_DIM + t] = beta[t];
    return;
  }
  int node = b * NB + vlist[b * NB + ci];
  int slot = b * NB + ci;

  __shared__ float aggL[HIDDEN];
  __shared__ float red[8];

  const float* rr = part + (size_t)slot * NSPL * REC;
  if (t < HIDDEN) {
    int h = t >> 4;
    float m0 = rr[128 + h], m1 = rr[REC + 128 + h];
    float m2 = rr[2 * REC + 128 + h], m3 = rr[3 * REC + 128 + h];
    float M = fmaxf(fmaxf(m0, m1), fmaxf(m2, m3));
    float e0 = __expf(m0 - M), e1 = __expf(m1 - M);
    float e2 = __expf(m2 - M), e3 = __expf(m3 - M);
    float l = e0 * rr[136 + h] + e1 * rr[REC + 136 + h] +
              e2 * rr[2 * REC + 136 + h] + e3 * rr[3 * REC + 136 + h];
    float num = e0 * rr[t] + e1 * rr[REC + t] +
                e2 * rr[2 * REC + t] + e3 * rr[3 * REC + t];
    aggL[t] = num / l;                 // l >= 1 for valid nodes
  }
  __syncthreads();

  {
    float y0 = bo[t], y1 = 0.f;
    const unsigned* wp = WoP + t;
    const float2* a2 = (const float2*)aggL;
#pragma unroll 4
    for (int k2 = 0; k2 < 64; ++k2) {
      F2H w;
      w.u = wp[(size_t)k2 * 256];
      float2 a = a2[k2];
      y0 = fmaf(a.x, (float)w.h.x, y0);
      y1 = fmaf(a.y, (float)w.h.y, y1);
    }
    float y = y0 + y1;
    float xv = nf[(size_t)node * NODE_DIM + t] + y;
    float s = xv, s2 = xv * xv;
    for (int off = 32; off; off >>= 1) {
      s += __shfl_down(s, off, 64);
      s2 += __shfl_down(s2, off, 64);
    }
    if ((t & 63) == 0) { red[t >> 6] = s; red[4 + (t >> 6)] = s2; }
    __syncthreads();
    s  = red[0] + red[1] + red[2] + red[3];
    s2 = red[4] + red[5] + red[6] + red[7];
    float mu = s * (1.0f / NODE_DIM);
    float var = fmaxf(s2 * (1.0f / NODE_DIM) - mu * mu, 0.0f);
    out[(size_t)node * NODE_DIM + t] =
        (xv - mu) * rsqrtf(var + 1e-5f) * gamma[t] + beta[t];
  }
}

extern "C" void kernel_launch(void* const* d_in, const int* in_sizes, int n_in,
                              void* d_out, int out_size, void* d_ws, size_t ws_size,
                              hipStream_t stream) {
  const float* nf    = (const float*)d_in[0];
  const float* pos   = (const float*)d_in[1];
  const int*   mask  = (const int*)  d_in[2];
  const float* Wq    = (const float*)d_in[3];
  const float* Wk    = (const float*)d_in[4];
  const float* Wv    = (const float*)d_in[5];
  const float* W1    = (const float*)d_in[6];
  const float* b1    = (const float*)d_in[7];
  const float* W2    = (const float*)d_in[8];
  const float* b2    = (const float*)d_in[9];
  const float* Wo    = (const float*)d_in[10];
  const float* bo    = (const float*)d_in[11];
  const float* gamma = (const float*)d_in[12];
  const float* beta  = (const float*)d_in[13];

  const int QKV = NNODES * HIDDEN;            // 196608

  float*    ws   = (float*)d_ws;
  float*    qc   = ws;
  f16*      kTcH = (f16*)(qc + QKV);
  f16*      vcH  = kTcH + QKV;
  unsigned* WoP  = (unsigned*)(vcH + QKV);
  float*    tab  = (float*)(WoP + 64 * 256);  // NR*NTH*4 floats (f16x8 entries)
  float*    tab0 = tab + NR * NTH * 4;        // 16 B
  float*    b2m  = tab0 + 4;
  float*    pcx  = b2m + 8;
  float*    pcy  = pcx + NNODES;
  int*      vlist= (int*)(pcy + NNODES);
  int*      mlist= vlist + NNODES;
  int*      cnt  = mlist + NNODES;
  float*    part = (float*)(cnt + 16);        // NSPL*NNODES*REC floats

  prep_kernel<<<NNODES / 4 + 4 + NTB, 256, 0, stream>>>(
      nf, pos, mask, Wq, Wk, Wv, W1, b1, W2, b2, Wo,
      qc, kTcH, vcH, WoP, tab, tab0, b2m, pcx, pcy, vlist, mlist, cnt);
  attn_part_kernel<<<2 * NNODES, 256, 0, stream>>>(
      pcx, pcy, cnt, tab, tab0, b2m, qc, kTcH, vcH, part);
  attn_merge_kernel<<<NNODES, 256, 0, stream>>>(
      cnt, vlist, mlist, part, WoP, nf, bo, gamma, beta, (float*)d_out);
}

// Round 9
// 115.971 us; speedup vs baseline: 1.0092x; 1.0092x over previous
//
#include <hip/hip_runtime.h>
#include <float.h>
#include <math.h>

#define NODE_DIM 256
#define HIDDEN   128
#define HEADS    8
#define HEAD_DIM 16
#define NB       768
#define BATCH    2
#define NNODES   (BATCH * NB)
#define SEPP     392   // f16 row stride: 784 B = 196 dwords, 196%32=4 (2-way, free)
#define REC      144   // partial record: 128 num + 8 m + 8 sum
#define NTH      128   // theta bins (power of 2, wraps)
#define NR       128   // radius bins
#define RMAX     16.0f
#define NTB      (NTH * NR / 256)   // table-build blocks (64)
#define NPT      12    // nodes per QKV tile (768 = 64*12)

typedef _Float16 f16;
typedef _Float16 h2 __attribute__((ext_vector_type(2)));
typedef __fp16 fp16x2 __attribute__((ext_vector_type(2)));
union F2H { float f; h2 h; unsigned u; };
union V4H { float4 f; h2 h[4]; };

__device__ __forceinline__ h2 pkrtz(float a, float b) {
  fp16x2 r = __builtin_amdgcn_cvt_pkrtz(a, b);   // v_cvt_pkrtz_f16_f32
  return __builtin_bit_cast(h2, r);
}

// GELU = u*Phi(u), Phi(u) ~ 0.5 + u*R(u^2), cubic fit on [-2.5,2.5].
__device__ __forceinline__ float gelu_poly(float u) {
  u = fminf(fmaxf(u, -2.5f), 2.5f);
  float t = u * u;
  float r = fmaf(t, -4.08639e-4f, 7.64400e-3f);
  r = fmaf(t, r, -6.40405e-2f);
  r = fmaf(t, r, 3.985355e-1f);
  return u * fmaf(u, r, 0.5f);
}

// Bilinear (theta, r)-table lookup of the 8-head edge bias; adds into the
// 8 score rows at column k0 (rows SEPP apart).
__device__ __forceinline__ void bias_lookup(
    const float* __restrict__ tab, const float* __restrict__ tab0,
    float dx, float dy, f16* __restrict__ row) {
  float sq = fmaf(dx, dx, dy * dy);
  float dist = __builtin_amdgcn_sqrtf(sq + 1e-6f);
  // fast atan2 (err ~1e-6 rad)
  float ax = fabsf(dx), ay = fabsf(dy);
  float mx = fmaxf(ax, ay), mn = fminf(ax, ay);
  float q = mn * __builtin_amdgcn_rcpf(mx);
  float s2 = q * q;
  float at = fmaf(s2, -0.01172120f, 0.05265332f);
  at = fmaf(s2, at, -0.11643287f);
  at = fmaf(s2, at, 0.19354346f);
  at = fmaf(s2, at, -0.33262347f);
  at = fmaf(s2, at, 0.99997726f);
  at = at * q;
  at = (ay > ax) ? (1.570796327f - at) : at;
  at = (dx < 0.f) ? (3.141592653f - at) : at;
  at = (dy < 0.f) ? -at : at;                    // theta in (-pi, pi]
  float tf = at * (0.1591549431f * (float)NTH);  // turns * NTH
  float tff = floorf(tf);
  float ft = tf - tff;
  int ti0 = (int)tff & (NTH - 1), ti1 = (ti0 + 1) & (NTH - 1);
  float rf = fminf(dist * ((float)(NR - 1) / RMAX), (float)(NR - 1) - 1e-3f);
  float rff = floorf(rf);
  float fr = rf - rff;
  int ri0 = (int)rff, ri1 = ri0 + 1;
  const float4* T4 = (const float4*)tab;
  V4H c00, c01, c10, c11;
  c00.f = T4[ri0 * NTH + ti0];
  c01.f = T4[ri0 * NTH + ti1];
  c10.f = T4[ri1 * NTH + ti0];
  c11.f = T4[ri1 * NTH + ti1];
  if (sq < 1e-12f) {      // degenerate (diagonal): exact tab0, kill NaN weights
    c00.f = *(const float4*)tab0;
    ft = 0.f; fr = 0.f;
  }
  float w11 = ft * fr, w10 = fr - w11, w01 = ft - w11;
  float w00 = 1.f - ft - fr + w11;
  h2 W00 = pkrtz(w00, w00), W01 = pkrtz(w01, w01);
  h2 W10 = pkrtz(w10, w10), W11 = pkrtz(w11, w11);
#pragma unroll
  for (int p = 0; p < 4; ++p) {
    h2 bb = c00.h[p] * W00 + c01.h[p] * W01;
    bb = c10.h[p] * W10 + bb;
    bb = c11.h[p] * W11 + bb;
    f16* r0p = row + (2 * p) * SEPP;
    f16* r1p = row + (2 * p + 1) * SEPP;
    *r0p = (f16)(*r0p + bb.x);
    *r1p = (f16)(*r1p + bb.y);
  }
}

// == K1: QKV tiled-GEMM (blocks 0..383: 3 mats x 128 node-tiles of 12)
//       + compaction (384,385) + b2m (386) + WoP (387)
//       + edge-bias table build (388..388+NTB-1) ==============================
__global__ __launch_bounds__(256) void prep_kernel(
    const float* __restrict__ nf, const float* __restrict__ pos,
    const int* __restrict__ mask,
    const float* __restrict__ Wq, const float* __restrict__ Wk,
    const float* __restrict__ Wv, const float* __restrict__ W1,
    const float* __restrict__ b1, const float* __restrict__ W2,
    const float* __restrict__ b2, const float* __restrict__ Wo,
    float* __restrict__ qc, f16* __restrict__ kTcH, f16* __restrict__ vcH,
    unsigned* __restrict__ WoP,
    float* __restrict__ tab, float* __restrict__ tab0,
    float* __restrict__ b2m,
    float* __restrict__ pcx, float* __restrict__ pcy,
    int* __restrict__ vlist, int* __restrict__ mlist, int* __restrict__ cnt) {
  int blk = blockIdx.x, t = threadIdx.x;

  if (blk < NNODES / 4) {           // 384 QKV blocks: m = blk/128, tile = blk%128
    int m = blk >> 7, tile = blk & 127;
    int b = tile >> 6, ti = tile & 63;
    int lo = ti * NPT;              // node offset within batch
    int n0g = b * NB + lo;          // global node base

    __shared__ float xs[NPT * NODE_DIM];   // 12 KB node features
    __shared__ float red2[NPT * HIDDEN];   // 6 KB cross-group partials
    __shared__ int accv;
    if (t == 0) accv = 0;
    __syncthreads();
    // mask prefix before this tile (for compacted slot index)
    for (int jb = 0; jb < lo; jb += 256) {
      int j = jb + t;
      int mv = (j < lo) && (mask[b * NB + j] != 0);
      unsigned long long ball = __ballot(mv);
      if ((t & 63) == 0) atomicAdd(&accv, __popcll(ball));
    }
    // stage 12 node rows into LDS (coalesced)
    for (int idx = t; idx < NPT * NODE_DIM; idx += 256)
      xs[idx] = nf[(size_t)n0g * NODE_DIM + idx];
    __syncthreads();

    int cb = accv;
    int mv[NPT], civ[NPT];
    int run = cb;
#pragma unroll
    for (int n = 0; n < NPT; ++n) {
      mv[n] = mask[n0g + n] != 0;
      civ[n] = run;
      run += mv[n];
    }

    const float* W = (m == 0) ? Wq : (m == 1) ? Wk : Wv;
    int c = t & 127, g = t >> 7;           // column, K-half
    float acc[NPT];
#pragma unroll
    for (int n = 0; n < NPT; ++n) acc[n] = 0.f;
    int kk0 = g * 128;
#pragma unroll 4
    for (int kk = kk0; kk < kk0 + 128; kk += 4) {
      float w0 = W[(kk + 0) * HIDDEN + c];
      float w1 = W[(kk + 1) * HIDDEN + c];
      float w2 = W[(kk + 2) * HIDDEN + c];
      float w3 = W[(kk + 3) * HIDDEN + c];
#pragma unroll
      for (int n = 0; n < NPT; ++n) {
        float4 x4 = *(const float4*)(xs + n * NODE_DIM + kk);
        acc[n] = fmaf(x4.x, w0, acc[n]);
        acc[n] = fmaf(x4.y, w1, acc[n]);
        acc[n] = fmaf(x4.z, w2, acc[n]);
        acc[n] = fmaf(x4.w, w3, acc[n]);
      }
    }
    if (g == 1) {
#pragma unroll
      for (int n = 0; n < NPT; ++n) red2[n * HIDDEN + c] = acc[n];
    }
    __syncthreads();
    if (g == 0) {
#pragma unroll
      for (int n = 0; n < NPT; ++n) {
        float v = acc[n] + red2[n * HIDDEN + c];
        if (mv[n]) {
          int slot = b * NB + civ[n];
          if (m == 0)      qc[(size_t)slot * HIDDEN + c] = v;
          else if (m == 1) kTcH[((size_t)b * HIDDEN + c) * NB + civ[n]] = (f16)v;
          else             vcH[(size_t)slot * HIDDEN + c] = (f16)v;
        }
      }
    }
  } else if (blk < NNODES / 4 + 2) {
    int b = blk - NNODES / 4;
    __shared__ int wcnt[4];
    __shared__ int base2[2];
    if (t < 2) base2[t] = 0;
    __syncthreads();
    int lane = t & 63, w = t >> 6;
    for (int iter = 0; iter < NB / 256; ++iter) {
      int j = iter * 256 + t;
      int mv = mask[b * NB + j] != 0;
      unsigned long long ball = __ballot(mv);
      if (lane == 0) wcnt[w] = __popcll(ball);
      __syncthreads();
      int pv = 0;
      for (int i = 0; i < w; ++i) pv += wcnt[i];
      int pin = (lane == 0) ? 0 : __popcll(ball & (~0ull >> (64 - lane)));
      if (mv) {
        int p = base2[0] + pv + pin;
        vlist[b * NB + p] = j;
        pcx[b * NB + p] = pos[(b * NB + j) * 2];
        pcy[b * NB + p] = pos[(b * NB + j) * 2 + 1];
      } else {
        int pm = base2[1] + (w * 64 - pv) + (lane - pin);
        mlist[b * NB + pm] = j;
      }
      __syncthreads();
      if (t == 0) {
        int tot = wcnt[0] + wcnt[1] + wcnt[2] + wcnt[3];
        base2[0] += tot;
        base2[1] += 256 - tot;
      }
      __syncthreads();
    }
    int nv = base2[0];
    if (t == 0) cnt[b] = nv;
    int nvp8 = (nv + 7) & ~7;
    if (t < HIDDEN)
      for (int col = nv; col < nvp8; ++col)
        kTcH[((size_t)b * HIDDEN + t) * NB + col] = (f16)0.0f;
  } else if (blk == NNODES / 4 + 2) {
    if (t < HEADS) {
      float s = 0.0f;
      for (int d = 0; d < HEAD_DIM; ++d) s += b2[t * HEAD_DIM + d];
      b2m[t] = s * (1.0f / 16.0f);
    }
  } else if (blk == NNODES / 4 + 3) {
    for (int k2 = 0; k2 < 64; ++k2) {
      F2H w;
      w.h = (h2){(f16)Wo[(2 * k2) * NODE_DIM + t],
                 (f16)Wo[(2 * k2 + 1) * NODE_DIM + t]};
      WoP[k2 * 256 + t] = w.u;
    }
  } else {
    // ---- edge-bias table: tab[ri][ti] = 8 x f16 of F(theta_ti, r_ri) ----
    int tblk = blk - (NNODES / 4 + 4);
    __shared__ float4 w1p[HIDDEN];           // {W1x, W1y, W1d, b1}
    __shared__ float  w2f[HIDDEN * 8];       // head-summed W2 / 16
    if (t < HIDDEN)
      w1p[t] = make_float4(W1[t], W1[HIDDEN + t], W1[2 * HIDDEN + t], b1[t]);
    for (int idx = t; idx < HIDDEN * 8; idx += 256) {
      int c = idx >> 3, h = idx & 7;
      float s = 0.f;
#pragma unroll
      for (int d = 0; d < HEAD_DIM; ++d) s += W2[c * HIDDEN + h * HEAD_DIM + d];
      w2f[idx] = s * (1.0f / 16.0f);
    }
    __syncthreads();
    int pid = tblk * 256 + t;
    int ti = pid & (NTH - 1), ri = pid >> 7;          // pid / NTH
    float th = (float)ti * (6.283185307f / (float)NTH);
    float r = (float)ri * (RMAX / (float)(NR - 1));
    float ux = __cosf(th), uy = __sinf(th);
    float acc[8] = {0, 0, 0, 0, 0, 0, 0, 0};
    for (int c = 0; c < HIDDEN; ++c) {
      float4 w = w1p[c];
      float u = fmaf(ux, w.x, fmaf(uy, w.y, fmaf(r, w.z, w.w)));
      float g = gelu_poly(u);
      const float4* wp = (const float4*)(w2f + c * 8);
      float4 wa = wp[0], wb = wp[1];
      acc[0] = fmaf(g, wa.x, acc[0]); acc[1] = fmaf(g, wa.y, acc[1]);
      acc[2] = fmaf(g, wa.z, acc[2]); acc[3] = fmaf(g, wa.w, acc[3]);
      acc[4] = fmaf(g, wb.x, acc[4]); acc[5] = fmaf(g, wb.y, acc[5]);
      acc[6] = fmaf(g, wb.z, acc[6]); acc[7] = fmaf(g, wb.w, acc[7]);
    }
    F2H p0, p1, p2, p3;
    p0.h = pkrtz(acc[0], acc[1]); p1.h = pkrtz(acc[2], acc[3]);
    p2.h = pkrtz(acc[4], acc[5]); p3.h = pkrtz(acc[6], acc[7]);
    ((float4*)tab)[ri * NTH + ti] = make_float4(p0.f, p1.f, p2.f, p3.f);
    if (tblk == 0 && t == 0) {
      // degenerate pair value: direction (0,0), dist = 1e-3
      float a0[8] = {0, 0, 0, 0, 0, 0, 0, 0};
      for (int c = 0; c < HIDDEN; ++c) {
        float4 w = w1p[c];
        float g = gelu_poly(fmaf(1e-3f, w.z, w.w));
        const float4* wp = (const float4*)(w2f + c * 8);
        float4 wa = wp[0], wb = wp[1];
        a0[0] = fmaf(g, wa.x, a0[0]); a0[1] = fmaf(g, wa.y, a0[1]);
        a0[2] = fmaf(g, wa.z, a0[2]); a0[3] = fmaf(g, wa.w, a0[3]);
        a0[4] = fmaf(g, wb.x, a0[4]); a0[5] = fmaf(g, wb.y, a0[5]);
        a0[6] = fmaf(g, wb.z, a0[6]); a0[7] = fmaf(g, wb.w, a0[7]);
      }
      F2H q0, q1, q2, q3;
      q0.h = pkrtz(a0[0], a0[1]); q1.h = pkrtz(a0[2], a0[3]);
      q2.h = pkrtz(a0[4], a0[5]); q3.h = pkrtz(a0[6], a0[7]);
      *(float4*)tab0 = make_float4(q0.f, q1.f, q2.f, q3.f);
    }
  }
}

// ===== K2a: split-K partial attention. 2 blocks per valid (b,ci). ==========
__global__ __launch_bounds__(256) void attn_part_kernel(
    const float* __restrict__ pcx, const float* __restrict__ pcy,
    const int* __restrict__ cnt, const float* __restrict__ tab,
    const float* __restrict__ tab0,
    const float* __restrict__ b2m, const float* __restrict__ qc,
    const f16* __restrict__ kTcH, const f16* __restrict__ vcH,
    float* __restrict__ part) {
  int half = blockIdx.x & 1, idx = blockIdx.x >> 1;
  int b = idx & 1, ci = idx >> 1;
  int t = threadIdx.x;
  int nv = cnt[b];
  if (ci >= nv) return;
  int slot = b * NB + ci;
  int H8 = (((nv + 1) >> 1) + 7) & ~7;      // 8-aligned half for f16x8 loads
  int klo = half * H8;
  int khi = min(nv, klo + H8);
  int kn = khi - klo;
  float* rec = part + ((size_t)slot * 2 + half) * REC;
  if (kn <= 0) {
    if (t < 128) rec[t] = 0.f;
    else if (t < 136) rec[t] = -3.0e38f;
    else if (t < 144) rec[t] = 0.f;
    return;
  }

  __shared__ __align__(16) unsigned char smem[15104];
  f16*   sE    = (f16*)smem;                   // [8][SEPP]  6272 B
  float* qs    = (float*)(smem + 6272);        // 512 B
  float* partD = (float*)(smem + 6784);        // [16][128]  8192 B
  float* ms    = (float*)(smem + 14976);       // 32 B
  float* ss    = (float*)(smem + 15008);       // 32 B

  if (t < HIDDEN) qs[t] = qc[(size_t)slot * HIDDEN + t];
  float pix = pcx[slot], piy = pcy[slot];
  __syncthreads();

  // ---- A: qk dots over this half's keys (8 heads x 32 lanes) ----
  {
    int h = t >> 5, l = t & 31;
    const f16* kb = kTcH + ((size_t)b * HIDDEN + h * 16) * NB + klo;
    h2 qp[16];
#pragma unroll
    for (int r = 0; r < 16; ++r) {
      f16 qh = (f16)qs[h * 16 + r];
      qp[r] = (h2){qh, qh};
    }
    h2 sc4 = {(f16)0.25f, (f16)0.25f};
    f16 bhh = (f16)b2m[h];
    h2 bh2 = {bhh, bhh};
    int n8 = (kn + 7) >> 3;
    for (int j8 = l; j8 < n8; j8 += 32) {
      h2 acc[4] = {{0, 0}, {0, 0}, {0, 0}, {0, 0}};
#pragma unroll
      for (int r = 0; r < 16; ++r) {
        V4H kv;
        kv.f = *(const float4*)(kb + (size_t)r * NB + j8 * 8);
        acc[0] += qp[r] * kv.h[0];
        acc[1] += qp[r] * kv.h[1];
        acc[2] += qp[r] * kv.h[2];
        acc[3] += qp[r] * kv.h[3];
      }
      V4H res;
#pragma unroll
      for (int p = 0; p < 4; ++p) res.h[p] = acc[p] * sc4 + bh2;
      *(float4*)(sE + h * SEPP + j8 * 8) = res.f;
    }
  }
  __syncthreads();

  // ---- B: edge-MLP bias via (theta, r) table, bilinear lookup ----
  for (int k0 = t; k0 < kn; k0 += 256) {
    int s0 = b * NB + klo + k0;
    bias_lookup(tab, tab0, pix - pcx[s0], piy - pcy[s0], sE + k0);
  }
  __syncthreads();

  // ---- C: local softmax stats per head; sE <- exp(s - m_local) ----
  {
    int h = t >> 5, l = t & 31;
    f16* row = sE + h * SEPP;
    float m = -FLT_MAX;
    for (int jj = l; jj < kn; jj += 32) m = fmaxf(m, (float)row[jj]);
    for (int off = 16; off; off >>= 1) m = fmaxf(m, __shfl_down(m, off, 32));
    m = __shfl(m, 0, 32);
    float s = 0.0f;
    for (int jj = l; jj < kn; jj += 32) {
      float e = __expf((float)row[jj] - m);
      row[jj] = (f16)e;
      s += e;
    }
    for (int off = 16; off; off >>= 1) s += __shfl_down(s, off, 32);
    if (l == 0) { ms[h] = m; ss[h] = s; }
  }
  __syncthreads();

  // ---- D: unnormalized weighted V over this half ----
  {
    int o8 = t & 15, g = t >> 4;
    int h = o8 >> 1;
    h2 acc[4] = {{0, 0}, {0, 0}, {0, 0}, {0, 0}};
    for (int jj = g; jj < kn; jj += 16) {
      V4H vv;
      vv.f = *(const float4*)(vcH + (size_t)(b * NB + klo + jj) * HIDDEN + o8 * 8);
      f16 w = sE[h * SEPP + jj];
      h2 ww = {w, w};
      acc[0] += ww * vv.h[0];
      acc[1] += ww * vv.h[1];
      acc[2] += ww * vv.h[2];
      acc[3] += ww * vv.h[3];
    }
    float* pd = partD + g * HIDDEN + o8 * 8;
    pd[0] = (float)acc[0].x; pd[1] = (float)acc[0].y;
    pd[2] = (float)acc[1].x; pd[3] = (float)acc[1].y;
    pd[4] = (float)acc[2].x; pd[5] = (float)acc[2].y;
    pd[6] = (float)acc[3].x; pd[7] = (float)acc[3].y;
  }
  __syncthreads();
  if (t < 128) {
    float s = 0.0f;
#pragma unroll
    for (int g = 0; g < 16; ++g) s += partD[g * HIDDEN + t];
    rec[t] = s;
  } else if (t < 136) {
    rec[t] = ms[t - 128];
  } else if (t < 144) {
    rec[t] = ss[t - 136];
  }
}

// ===== K2b: flash merge of 2 partials + out-proj + residual + LayerNorm =====
__global__ __launch_bounds__(256) void attn_merge_kernel(
    const int* __restrict__ cnt, const int* __restrict__ vlist,
    const int* __restrict__ mlist, const float* __restrict__ part,
    const unsigned* __restrict__ WoP, const float* __restrict__ nf,
    const float* __restrict__ bo, const float* __restrict__ gamma,
    const float* __restrict__ beta, float* __restrict__ out) {
  int b = blockIdx.x & 1, ci = blockIdx.x >> 1;
  int t = threadIdx.x;
  int nv = cnt[b];
  if (ci >= nv) {                      // masked node -> x==0 -> LN gives beta
    int node = b * NB + mlist[b * NB + (ci - nv)];
    out[(size_t)node * NODE_DIM + t] = beta[t];
    return;
  }
  int node = b * NB + vlist[b * NB + ci];
  int slot = b * NB + ci;

  __shared__ float aggL[HIDDEN];
  __shared__ float red[8];

  const float* r0 = part + (size_t)slot * 2 * REC;
  const float* r1 = r0 + REC;
  if (t < HIDDEN) {
    int h = t >> 4;
    float m0 = r0[128 + h], m1 = r1[128 + h];
    float M = fmaxf(m0, m1);
    float e0 = __expf(m0 - M), e1 = __expf(m1 - M);
    float l = fmaf(e0, r0[136 + h], e1 * r1[136 + h]);
    aggL[t] = fmaf(e0, r0[t], e1 * r1[t]) / l;
  }
  __syncthreads();

  {
    float y0 = bo[t], y1 = 0.f;
    const unsigned* wp = WoP + t;
    const float2* a2 = (const float2*)aggL;
#pragma unroll 4
    for (int k2 = 0; k2 < 64; ++k2) {
      F2H w;
      w.u = wp[(size_t)k2 * 256];
      float2 a = a2[k2];
      y0 = fmaf(a.x, (float)w.h.x, y0);
      y1 = fmaf(a.y, (float)w.h.y, y1);
    }
    float y = y0 + y1;
    float xv = nf[(size_t)node * NODE_DIM + t] + y;
    float s = xv, s2 = xv * xv;
    for (int off = 32; off; off >>= 1) {
      s += __shfl_down(s, off, 64);
      s2 += __shfl_down(s2, off, 64);
    }
    if ((t & 63) == 0) { red[t >> 6] = s; red[4 + (t >> 6)] = s2; }
    __syncthreads();
    s  = red[0] + red[1] + red[2] + red[3];
    s2 = red[4] + red[5] + red[6] + red[7];
    float mu = s * (1.0f / NODE_DIM);
    float var = fmaxf(s2 * (1.0f / NODE_DIM) - mu * mu, 0.0f);
    out[(size_t)node * NODE_DIM + t] =
        (xv - mu) * rsqrtf(var + 1e-5f) * gamma[t] + beta[t];
  }
}

extern "C" void kernel_launch(void* const* d_in, const int* in_sizes, int n_in,
                              void* d_out, int out_size, void* d_ws, size_t ws_size,
                              hipStream_t stream) {
  const float* nf    = (const float*)d_in[0];
  const float* pos   = (const float*)d_in[1];
  const int*   mask  = (const int*)  d_in[2];
  const float* Wq    = (const float*)d_in[3];
  const float* Wk    = (const float*)d_in[4];
  const float* Wv    = (const float*)d_in[5];
  const float* W1    = (const float*)d_in[6];
  const float* b1    = (const float*)d_in[7];
  const float* W2    = (const float*)d_in[8];
  const float* b2    = (const float*)d_in[9];
  const float* Wo    = (const float*)d_in[10];
  const float* bo    = (const float*)d_in[11];
  const float* gamma = (const float*)d_in[12];
  const float* beta  = (const float*)d_in[13];

  const int QKV = NNODES * HIDDEN;            // 196608

  float*    ws   = (float*)d_ws;
  float*    qc   = ws;
  f16*      kTcH = (f16*)(qc + QKV);
  f16*      vcH  = kTcH + QKV;
  unsigned* WoP  = (unsigned*)(vcH + QKV);
  float*    tab  = (float*)(WoP + 64 * 256);  // NR*NTH*4 floats (f16x8 entries)
  float*    tab0 = tab + NR * NTH * 4;        // 16 B
  float*    b2m  = tab0 + 4;
  float*    pcx  = b2m + 8;
  float*    pcy  = pcx + NNODES;
  int*      vlist= (int*)(pcy + NNODES);
  int*      mlist= vlist + NNODES;
  int*      cnt  = mlist + NNODES;
  float*    part = (float*)(cnt + 16);        // 2*NNODES*REC floats

  prep_kernel<<<NNODES / 4 + 4 + NTB, 256, 0, stream>>>(
      nf, pos, mask, Wq, Wk, Wv, W1, b1, W2, b2, Wo,
      qc, kTcH, vcH, WoP, tab, tab0, b2m, pcx, pcy, vlist, mlist, cnt);
  attn_part_kernel<<<2 * NNODES, 256, 0, stream>>>(
      pcx, pcy, cnt, tab, tab0, b2m, qc, kTcH, vcH, part);
  attn_merge_kernel<<<NNODES, 256, 0, stream>>>(
      cnt, vlist, mlist, part, WoP, nf, bo, gamma, beta, (float*)d_out);
}